// Round 8
// baseline (110.821 us; speedup 1.0000x reference)
//
#include <hip/hip_runtime.h>
#include <math.h>

#define DD 128
#define NSPLIT 16
#define NBINS 512
#define SHIFT 10.0f
#define L2E_T 14.4269504089f   // 10 * log2(e)

typedef _Float16 f16x8 __attribute__((ext_vector_type(8)));
typedef _Float16 f16x2 __attribute__((ext_vector_type(2)));
typedef float f32x4 __attribute__((ext_vector_type(4)));

// ---- normalize rows -> f16, labels, histogram; also zeroes d_out ----
__global__ __launch_bounds__(256)
void norm_kernel(const float* __restrict__ f, const int* __restrict__ labels,
                 _Float16* __restrict__ fh, int* __restrict__ labm,
                 int* __restrict__ hist, float* __restrict__ out, int M, int nrep)
{
    if (blockIdx.x == 0 && threadIdx.x == 0) out[0] = 0.f;  // final runs 2 kernels later
    int gw = (blockIdx.x * 256 + threadIdx.x) >> 6;   // one wave per row
    int lane = threadIdx.x & 63;
    if (gw >= M) return;
    float2 v = *reinterpret_cast<const float2*>(&f[(size_t)gw * DD + lane * 2]);
    float ss = v.x * v.x + v.y * v.y;
    #pragma unroll
    for (int m = 1; m < 64; m <<= 1) ss += __shfl_xor(ss, m);
    float inv = 1.0f / fmaxf(sqrtf(ss), 1e-12f);
    f16x2 h; h[0] = (_Float16)(v.x * inv); h[1] = (_Float16)(v.y * inv);
    *reinterpret_cast<f16x2*>(&fh[(size_t)gw * DD + lane * 2]) = h;
    if (lane == 0) {
        int lb = labels[gw / nrep];
        labm[gw] = lb;
        if ((gw % nrep) == 0) atomicAdd(&hist[lb], nrep);  // one atomic per sample
    }
}

// ---- main: barrier-free f16 MFMA stream, software-pipelined j-subtiles ----
// 4 waves/block, no LDS, no barriers. Wave owns 32 register-resident i-rows
// (bfr[2][4] = 32 regs; total demand ~110 unified regs -> (256,4) fits, no
// spill). j streams as 16-row subtiles, 2x-unrolled ping-pong (af0/af1):
// per half-iter {8 MFMA on cur} -> {issue next 4 loads} -> {exp2 epilogue},
// so next tile's L2 latency hides under the ~450-cyc epilogue.
// Grid 1024 = 4 blocks/CU = 4 waves/SIMD, single uniform round (R7 was
// 2 waves/SIMD and latency-bound at 18% occupancy).
// S^T via mfma(A=Fj, B=Fi): i = lane&15 (lane-local), j = (lane>>4)*4 + r.
// Self-pair included; final kernel subtracts it exactly.
__global__ __launch_bounds__(256, 4)
void supcon_main(const _Float16* __restrict__ fh, const int* __restrict__ labm,
                 float* __restrict__ Epart, float* __restrict__ Ppart,
                 int M, int jchunk)
{
    const int lane = threadIdx.x & 63;
    const int w = threadIdx.x >> 6;
    const int ibase = blockIdx.x * 128 + w * 32;
    const int rowsel = lane & 15;
    const int grp = lane >> 4;
    const int ksel = grp * 8;      // f16 k-offset within a 32-wide K step

    // register-resident Fi fragments: 2 subtiles x 4 K-steps = 32 regs
    f16x8 bfr[2][4];
    #pragma unroll
    for (int t = 0; t < 2; ++t)
        #pragma unroll
        for (int kk = 0; kk < 4; ++kk)
            bfr[t][kk] = *reinterpret_cast<const f16x8*>(
                &fh[(size_t)(ibase + t * 16 + rowsel) * DD + kk * 32 + ksel]);

    int li[2];
    #pragma unroll
    for (int t = 0; t < 2; ++t) li[t] = labm[ibase + t * 16 + rowsel];

    float esum[2] = {0.f, 0.f};
    float psum[2] = {0.f, 0.f};

    const int j0 = blockIdx.y * jchunk;
    const _Float16* aptr = fh + (size_t)(j0 + rowsel) * DD + ksel;
    const int* lptr = labm + j0 + grp * 4;
    const int nsub = jchunk >> 4;      // 32 subtiles (even)

#define LOADT(A, L, s) { \
    _Pragma("unroll") for (int kk = 0; kk < 4; ++kk) \
        A[kk] = *reinterpret_cast<const f16x8*>(aptr + (size_t)(s) * 16 * DD + kk * 32); \
    L = *reinterpret_cast<const int4*>(lptr + (s) * 16); }

#define MFMA8(A, c0, c1) { \
    _Pragma("unroll") for (int kk = 0; kk < 4; ++kk) { \
        c0 = __builtin_amdgcn_mfma_f32_16x16x32_f16(A[kk], bfr[0][kk], c0, 0, 0, 0); \
        c1 = __builtin_amdgcn_mfma_f32_16x16x32_f16(A[kk], bfr[1][kk], c1, 0, 0, 0); } }

#define EPI1(t, cc, L) { \
    float e0 = exp2f(__builtin_fmaf(cc[0], L2E_T, -L2E_T)); \
    float e1 = exp2f(__builtin_fmaf(cc[1], L2E_T, -L2E_T)); \
    float e2 = exp2f(__builtin_fmaf(cc[2], L2E_T, -L2E_T)); \
    float e3 = exp2f(__builtin_fmaf(cc[3], L2E_T, -L2E_T)); \
    esum[t] += (e0 + e1) + (e2 + e3); \
    float p0 = (L.x == li[t]) ? cc[0] : 0.f; \
    float p1 = (L.y == li[t]) ? cc[1] : 0.f; \
    float p2 = (L.z == li[t]) ? cc[2] : 0.f; \
    float p3 = (L.w == li[t]) ? cc[3] : 0.f; \
    psum[t] += (p0 + p1) + (p2 + p3); }

    f16x8 af0[4], af1[4];
    int4 lj0, lj1;
    LOADT(af0, lj0, 0);

    for (int s = 0; s < nsub; s += 2) {
        {   // subtile s (af0); prefetch s+1 between MFMA and epilogue
            f32x4 c0 = {0,0,0,0}, c1 = {0,0,0,0};
            MFMA8(af0, c0, c1);
            LOADT(af1, lj1, s + 1);          // nsub even: s+1 always valid
            EPI1(0, c0, lj0); EPI1(1, c1, lj0);
        }
        {   // subtile s+1 (af1); prefetch s+2
            f32x4 c0 = {0,0,0,0}, c1 = {0,0,0,0};
            MFMA8(af1, c0, c1);
            if (s + 2 < nsub) LOADT(af0, lj0, s + 2);
            EPI1(0, c0, lj1); EPI1(1, c1, lj1);
        }
    }
#undef LOADT
#undef MFMA8
#undef EPI1

    // fold lane groups (bits 4,5 = different j rows of the same i)
    #pragma unroll
    for (int t = 0; t < 2; ++t) {
        float e = esum[t], p = psum[t];
        e += __shfl_xor(e, 16); e += __shfl_xor(e, 32);
        p += __shfl_xor(p, 16); p += __shfl_xor(p, 32);
        if (lane < 16) {
            size_t o = (size_t)blockIdx.y * M + ibase + t * 16 + lane;
            Epart[o] = e;
            Ppart[o] = p;
        }
    }
}

// ---- per-row loss term (exact self-term subtraction) + global reduce ----
__global__ __launch_bounds__(256)
void final_fused(const _Float16* __restrict__ fh, const float* __restrict__ Epart,
                 const float* __restrict__ Ppart, const int* __restrict__ labm,
                 const int* __restrict__ hist, float* __restrict__ out, int M)
{
    __shared__ float red[4];
    int i = (blockIdx.x * 256 + threadIdx.x) >> 6;   // wave per row
    int lane = threadIdx.x & 63;
    f16x2 h = *reinterpret_cast<const f16x2*>(&fh[(size_t)i * DD + lane * 2]);
    float x0 = (float)h[0], x1 = (float)h[1];
    float aii = x0 * x0 + x1 * x1;                   // f16 self-dot in fp32
    #pragma unroll
    for (int m = 1; m < 64; m <<= 1) aii += __shfl_xor(aii, m);
    float ep = 0.f;
    if (lane < NSPLIT) ep = Epart[(size_t)lane * M + i];
    else if (lane >= 32 && lane < 32 + NSPLIT) ep = Ppart[(size_t)(lane - 32) * M + i];
    #pragma unroll
    for (int m = 1; m < 32; m <<= 1) ep += __shfl_xor(ep, m);  // within 32-halves
    float P = __shfl(ep, 32);
    float term = 0.f;
    if (lane == 0) {
        int lb = labm[i];
        float cnt = (float)(hist[lb] - 1);
        float E = ep - exp2f(__builtin_fmaf(aii, L2E_T, -L2E_T)); // drop self exp
        float Pc = SHIFT * (P - aii);                              // drop self dot
        term = (SHIFT + logf(E)) - Pc / cnt;
    }
    int wv = threadIdx.x >> 6;
    if (lane == 0) red[wv] = term;
    __syncthreads();
    if (threadIdx.x == 0)
        atomicAdd(out, (red[0] + red[1] + red[2] + red[3]) / (float)M);
}

extern "C" void kernel_launch(void* const* d_in, const int* in_sizes, int n_in,
                              void* d_out, int out_size, void* d_ws, size_t ws_size,
                              hipStream_t stream)
{
    const float* feats = (const float*)d_in[0];
    const int* labels = (const int*)d_in[1];
    const int Bn = in_sizes[1];
    const int M = in_sizes[0] / DD;    // 8192
    const int nrep = M / Bn;           // 2

    char* ws = (char*)d_ws;
    _Float16* fh = (_Float16*)ws;
    size_t off = (size_t)M * DD * sizeof(_Float16);
    int* labm = (int*)(ws + off); off += (size_t)M * sizeof(int);
    int* hist = (int*)(ws + off); off += (size_t)NBINS * sizeof(int);
    off = (off + 255) & ~(size_t)255;
    float* Epart = (float*)(ws + off); off += (size_t)NSPLIT * M * sizeof(float);
    float* Ppart = (float*)(ws + off); off += (size_t)NSPLIT * M * sizeof(float);

    hipMemsetAsync(hist, 0, NBINS * sizeof(int), stream);

    norm_kernel<<<M / 4, 256, 0, stream>>>(feats, labels, fh, labm, hist,
                                           (float*)d_out, M, nrep);

    const int jchunk = M / NSPLIT;     // 512 -> 32 subtiles per wave
    dim3 grid(M / 128, NSPLIT);        // 64 x 16 = 1024 blocks (4/CU, 1 round)
    supcon_main<<<grid, 256, 0, stream>>>(fh, labm, Epart, Ppart, M, jchunk);

    final_fused<<<M / 4, 256, 0, stream>>>(fh, Epart, Ppart, labm, hist, (float*)d_out, M);
}

// Round 9
// 94.689 us; speedup vs baseline: 1.1704x; 1.1704x over previous
//
#include <hip/hip_runtime.h>
#include <math.h>

#define DD 128
#define NSPLIT 16
#define NBINS 512
#define SHIFT 10.0f
#define L2E_T 14.4269504089f   // 10 * log2(e)

typedef _Float16 f16x8 __attribute__((ext_vector_type(8)));
typedef _Float16 f16x2 __attribute__((ext_vector_type(2)));
typedef float f32x4 __attribute__((ext_vector_type(4)));

// guard-free 2^x: args are in [-29, 0], no denorm/overflow concerns
__device__ __forceinline__ float ex2(float x) {
#if __has_builtin(__builtin_amdgcn_exp2f)
    return __builtin_amdgcn_exp2f(x);
#else
    return exp2f(x);
#endif
}

// ---- normalize rows -> f16, labels, histogram; also zeroes d_out ----
__global__ __launch_bounds__(256)
void norm_kernel(const float* __restrict__ f, const int* __restrict__ labels,
                 _Float16* __restrict__ fh, int* __restrict__ labm,
                 int* __restrict__ hist, float* __restrict__ out, int M, int nrep)
{
    if (blockIdx.x == 0 && threadIdx.x == 0) out[0] = 0.f;  // final runs 2 kernels later
    int gw = (blockIdx.x * 256 + threadIdx.x) >> 6;   // one wave per row
    int lane = threadIdx.x & 63;
    if (gw >= M) return;
    float2 v = *reinterpret_cast<const float2*>(&f[(size_t)gw * DD + lane * 2]);
    float ss = v.x * v.x + v.y * v.y;
    #pragma unroll
    for (int m = 1; m < 64; m <<= 1) ss += __shfl_xor(ss, m);
    float inv = 1.0f / fmaxf(sqrtf(ss), 1e-12f);
    f16x2 h; h[0] = (_Float16)(v.x * inv); h[1] = (_Float16)(v.y * inv);
    *reinterpret_cast<f16x2*>(&fh[(size_t)gw * DD + lane * 2]) = h;
    if (lane == 0) {
        int lb = labels[gw / nrep];
        labm[gw] = lb;
        if ((gw % nrep) == 0) atomicAdd(&hist[lb], nrep);  // one atomic per sample
    }
}

// ---- main: barrier-free f16 MFMA stream, 2-deep acc pipeline (T15) ----
// R7 config (best measured): 4 waves/block, 64 i-rows/wave register-resident,
// 512 blocks = 2/CU, (256,3). New: two named acc sets (A*, B*); MFMA of tile
// s+1 is issued BEFORE the epilogue of tile s. Fresh zero-init accs make the
// new MFMA chain independent of the old EPI, so the scheduler interleaves
// matrix-pipe and VALU streams within one wave (m114 overlap). exp2 via raw
// v_exp_f32 (no OCML denorm guard) cuts the epilogue ~10->6 ops/logit.
// S^T via mfma(A=Fj, B=Fi): i = lane&15 (lane-local), j = (lane>>4)*4 + r.
// Self-pair included; final kernel subtracts it exactly.
__global__ __launch_bounds__(256, 3)
void supcon_main(const _Float16* __restrict__ fh, const int* __restrict__ labm,
                 float* __restrict__ Epart, float* __restrict__ Ppart,
                 int M, int jchunk)
{
    const int lane = threadIdx.x & 63;
    const int w = threadIdx.x >> 6;
    const int ibase = blockIdx.x * 256 + w * 64;
    const int rowsel = lane & 15;
    const int grp = lane >> 4;
    const int ksel = grp * 8;      // f16 k-offset within a 32-wide K step

    // register-resident Fi fragments: 4 subtiles x 4 K-steps = 64 regs
    f16x8 bfr[4][4];
    #pragma unroll
    for (int t = 0; t < 4; ++t)
        #pragma unroll
        for (int kk = 0; kk < 4; ++kk)
            bfr[t][kk] = *reinterpret_cast<const f16x8*>(
                &fh[(size_t)(ibase + t * 16 + rowsel) * DD + kk * 32 + ksel]);

    int li[4];
    #pragma unroll
    for (int t = 0; t < 4; ++t) li[t] = labm[ibase + t * 16 + rowsel];

    float esum[4] = {0.f, 0.f, 0.f, 0.f};
    float psum[4] = {0.f, 0.f, 0.f, 0.f};

    const int j0 = blockIdx.y * jchunk;
    const _Float16* aptr = fh + (size_t)(j0 + rowsel) * DD + ksel;
    const int* lptr = labm + j0 + grp * 4;
    const int nsub = jchunk >> 4;      // 32 subtiles (even)

#define LOADT(A, L, s) { \
    _Pragma("unroll") for (int kk = 0; kk < 4; ++kk) \
        A[kk] = *reinterpret_cast<const f16x8*>(aptr + (size_t)(s) * 16 * DD + kk * 32); \
    L = *reinterpret_cast<const int4*>(lptr + (s) * 16); }

#define MFMA_T(A, c0, c1, c2, c3) { \
    c0 = (f32x4){0.f,0.f,0.f,0.f}; c1 = (f32x4){0.f,0.f,0.f,0.f}; \
    c2 = (f32x4){0.f,0.f,0.f,0.f}; c3 = (f32x4){0.f,0.f,0.f,0.f}; \
    _Pragma("unroll") for (int kk = 0; kk < 4; ++kk) { \
        c0 = __builtin_amdgcn_mfma_f32_16x16x32_f16(A[kk], bfr[0][kk], c0, 0, 0, 0); \
        c1 = __builtin_amdgcn_mfma_f32_16x16x32_f16(A[kk], bfr[1][kk], c1, 0, 0, 0); \
        c2 = __builtin_amdgcn_mfma_f32_16x16x32_f16(A[kk], bfr[2][kk], c2, 0, 0, 0); \
        c3 = __builtin_amdgcn_mfma_f32_16x16x32_f16(A[kk], bfr[3][kk], c3, 0, 0, 0); } }

#define EPI1(t, cc, L) { \
    esum[t] += (ex2(__builtin_fmaf(cc[0], L2E_T, -L2E_T)) \
              + ex2(__builtin_fmaf(cc[1], L2E_T, -L2E_T))) \
             + (ex2(__builtin_fmaf(cc[2], L2E_T, -L2E_T)) \
              + ex2(__builtin_fmaf(cc[3], L2E_T, -L2E_T))); \
    float p0 = (L.x == li[t]) ? cc[0] : 0.f; \
    float p1 = (L.y == li[t]) ? cc[1] : 0.f; \
    float p2 = (L.z == li[t]) ? cc[2] : 0.f; \
    float p3 = (L.w == li[t]) ? cc[3] : 0.f; \
    psum[t] += (p0 + p1) + (p2 + p3); }

#define EPI4(c0, c1, c2, c3, L) { \
    EPI1(0, c0, L); EPI1(1, c1, L); EPI1(2, c2, L); EPI1(3, c3, L); }

    f16x8 af0[4], af1[4];
    int4 ljA, ljB;
    f32x4 A0, A1, A2, A3, B0, B1, B2, B3;

    LOADT(af0, ljA, 0);
    MFMA_T(af0, A0, A1, A2, A3);       // tile 0 in flight
    LOADT(af1, ljB, 1);

    for (int s = 0; s < nsub - 2; s += 2) {
        MFMA_T(af1, B0, B1, B2, B3);   // tile s+1 issues first
        int4 ljA2; LOADT(af0, ljA2, s + 2);   // af0 free: its MFMAs issued
        EPI4(A0, A1, A2, A3, ljA);     // tile s epi covers B-chain + af0 load
        ljA = ljA2;
        MFMA_T(af0, A0, A1, A2, A3);   // tile s+2 (af0 just landed)
        int4 ljB2; LOADT(af1, ljB2, s + 3);
        EPI4(B0, B1, B2, B3, ljB);     // tile s+1 epi covers A-chain + af1 load
        ljB = ljB2;
    }
    MFMA_T(af1, B0, B1, B2, B3);       // tile nsub-1
    EPI4(A0, A1, A2, A3, ljA);         // tile nsub-2
    EPI4(B0, B1, B2, B3, ljB);         // tile nsub-1
#undef LOADT
#undef MFMA_T
#undef EPI1
#undef EPI4

    // fold lane groups (bits 4,5 = different j rows of the same i)
    #pragma unroll
    for (int t = 0; t < 4; ++t) {
        float e = esum[t], p = psum[t];
        e += __shfl_xor(e, 16); e += __shfl_xor(e, 32);
        p += __shfl_xor(p, 16); p += __shfl_xor(p, 32);
        if (lane < 16) {
            size_t o = (size_t)blockIdx.y * M + ibase + t * 16 + lane;
            Epart[o] = e;
            Ppart[o] = p;
        }
    }
}

// ---- per-row loss term (exact self-term subtraction) + global reduce ----
__global__ __launch_bounds__(256)
void final_fused(const _Float16* __restrict__ fh, const float* __restrict__ Epart,
                 const float* __restrict__ Ppart, const int* __restrict__ labm,
                 const int* __restrict__ hist, float* __restrict__ out, int M)
{
    __shared__ float red[4];
    int i = (blockIdx.x * 256 + threadIdx.x) >> 6;   // wave per row
    int lane = threadIdx.x & 63;
    f16x2 h = *reinterpret_cast<const f16x2*>(&fh[(size_t)i * DD + lane * 2]);
    float x0 = (float)h[0], x1 = (float)h[1];
    float aii = x0 * x0 + x1 * x1;                   // f16 self-dot in fp32
    #pragma unroll
    for (int m = 1; m < 64; m <<= 1) aii += __shfl_xor(aii, m);
    float ep = 0.f;
    if (lane < NSPLIT) ep = Epart[(size_t)lane * M + i];
    else if (lane >= 32 && lane < 32 + NSPLIT) ep = Ppart[(size_t)(lane - 32) * M + i];
    #pragma unroll
    for (int m = 1; m < 32; m <<= 1) ep += __shfl_xor(ep, m);  // within 32-halves
    float P = __shfl(ep, 32);
    float term = 0.f;
    if (lane == 0) {
        int lb = labm[i];
        float cnt = (float)(hist[lb] - 1);
        float E = ep - ex2(__builtin_fmaf(aii, L2E_T, -L2E_T));  // drop self exp
        float Pc = SHIFT * (P - aii);                            // drop self dot
        term = (SHIFT + logf(E)) - Pc / cnt;
    }
    int wv = threadIdx.x >> 6;
    if (lane == 0) red[wv] = term;
    __syncthreads();
    if (threadIdx.x == 0)
        atomicAdd(out, (red[0] + red[1] + red[2] + red[3]) / (float)M);
}

extern "C" void kernel_launch(void* const* d_in, const int* in_sizes, int n_in,
                              void* d_out, int out_size, void* d_ws, size_t ws_size,
                              hipStream_t stream)
{
    const float* feats = (const float*)d_in[0];
    const int* labels = (const int*)d_in[1];
    const int Bn = in_sizes[1];
    const int M = in_sizes[0] / DD;    // 8192
    const int nrep = M / Bn;           // 2

    char* ws = (char*)d_ws;
    _Float16* fh = (_Float16*)ws;
    size_t off = (size_t)M * DD * sizeof(_Float16);
    int* labm = (int*)(ws + off); off += (size_t)M * sizeof(int);
    int* hist = (int*)(ws + off); off += (size_t)NBINS * sizeof(int);
    off = (off + 255) & ~(size_t)255;
    float* Epart = (float*)(ws + off); off += (size_t)NSPLIT * M * sizeof(float);
    float* Ppart = (float*)(ws + off); off += (size_t)NSPLIT * M * sizeof(float);

    hipMemsetAsync(hist, 0, NBINS * sizeof(int), stream);

    norm_kernel<<<M / 4, 256, 0, stream>>>(feats, labels, fh, labm, hist,
                                           (float*)d_out, M, nrep);

    const int jchunk = M / NSPLIT;     // 512 -> 32 subtiles per wave
    dim3 grid(M / 256, NSPLIT);        // 32 x 16 = 512 blocks (2/CU, 1 round)
    supcon_main<<<grid, 256, 0, stream>>>(fh, labm, Epart, Ppart, M, jchunk);

    final_fused<<<M / 4, 256, 0, stream>>>(fh, Epart, Ppart, labm, hist, (float*)d_out, M);
}

// Round 10
// 85.825 us; speedup vs baseline: 1.2913x; 1.1033x over previous
//
#include <hip/hip_runtime.h>
#include <math.h>

#define DD 128
#define NSPLIT 16
#define NBINS 512
#define SHIFT 10.0f
#define L2E_T 14.4269504089f   // 10 * log2(e)

typedef _Float16 f16x8 __attribute__((ext_vector_type(8)));
typedef _Float16 f16x2 __attribute__((ext_vector_type(2)));
typedef float f32x4 __attribute__((ext_vector_type(4)));

// guard-free 2^x: args are in [-29, 0], no denorm/overflow concerns
__device__ __forceinline__ float ex2(float x) {
#if __has_builtin(__builtin_amdgcn_exp2f)
    return __builtin_amdgcn_exp2f(x);
#else
    return exp2f(x);
#endif
}

// ---- normalize rows -> f16, labels, histogram, label-sums G; zeroes d_out ----
__global__ __launch_bounds__(256)
void norm_kernel(const float* __restrict__ f, const int* __restrict__ labels,
                 _Float16* __restrict__ fh, int* __restrict__ labm,
                 int* __restrict__ hist, float* __restrict__ G,
                 float* __restrict__ out, int M, int nrep)
{
    if (blockIdx.x == 0 && threadIdx.x == 0) out[0] = 0.f;  // final runs 2 kernels later
    int gw = (blockIdx.x * 256 + threadIdx.x) >> 6;   // one wave per row
    int lane = threadIdx.x & 63;
    if (gw >= M) return;
    float2 v = *reinterpret_cast<const float2*>(&f[(size_t)gw * DD + lane * 2]);
    float ss = v.x * v.x + v.y * v.y;
    #pragma unroll
    for (int m = 1; m < 64; m <<= 1) ss += __shfl_xor(ss, m);
    float inv = 1.0f / fmaxf(sqrtf(ss), 1e-12f);
    float ox = v.x * inv, oy = v.y * inv;
    f16x2 h; h[0] = (_Float16)ox; h[1] = (_Float16)oy;
    *reinterpret_cast<f16x2*>(&fh[(size_t)gw * DD + lane * 2]) = h;
    int lb = labels[gw / nrep];
    atomicAdd(&G[lb * DD + lane * 2],     ox);
    atomicAdd(&G[lb * DD + lane * 2 + 1], oy);
    if (lane == 0) {
        labm[gw] = lb;
        if ((gw % nrep) == 0) atomicAdd(&hist[lb], nrep);  // one atomic per sample
    }
}

// ---- main: barrier-free f16 MFMA stream; epilogue = exp-sum ONLY ----
// R7's proven schedule (4 waves/block, 64 i-rows register-resident, 512
// blocks = 2/CU, (256,3), 2x ping-pong af0/af1 with prefetch between MFMA
// and epilogue). P-sum moved out of the hot loop via G (final kernel):
// epilogue is 3 ops/logit (fma, raw v_exp_f32, add) - no labels, no cmp,
// no cndmask. Self-pair included; final kernel subtracts it exactly.
__global__ __launch_bounds__(256, 3)
void supcon_main(const _Float16* __restrict__ fh, float* __restrict__ Epart,
                 int M, int jchunk)
{
    const int lane = threadIdx.x & 63;
    const int w = threadIdx.x >> 6;
    const int ibase = blockIdx.x * 256 + w * 64;
    const int rowsel = lane & 15;
    const int ksel = (lane >> 4) * 8;  // f16 k-offset within a 32-wide K step

    // register-resident Fi fragments: 4 subtiles x 4 K-steps = 64 regs
    f16x8 bfr[4][4];
    #pragma unroll
    for (int t = 0; t < 4; ++t)
        #pragma unroll
        for (int kk = 0; kk < 4; ++kk)
            bfr[t][kk] = *reinterpret_cast<const f16x8*>(
                &fh[(size_t)(ibase + t * 16 + rowsel) * DD + kk * 32 + ksel]);

    float esum[4] = {0.f, 0.f, 0.f, 0.f};

    const int j0 = blockIdx.y * jchunk;
    const _Float16* aptr = fh + (size_t)(j0 + rowsel) * DD + ksel;
    const int nsub = jchunk >> 4;      // 32 subtiles (even)

#define LOADT(A, s) { \
    _Pragma("unroll") for (int kk = 0; kk < 4; ++kk) \
        A[kk] = *reinterpret_cast<const f16x8*>(aptr + (size_t)(s) * 16 * DD + kk * 32); }

#define MFMA16(A, c0, c1, c2, c3) { \
    _Pragma("unroll") for (int kk = 0; kk < 4; ++kk) { \
        c0 = __builtin_amdgcn_mfma_f32_16x16x32_f16(A[kk], bfr[0][kk], c0, 0, 0, 0); \
        c1 = __builtin_amdgcn_mfma_f32_16x16x32_f16(A[kk], bfr[1][kk], c1, 0, 0, 0); \
        c2 = __builtin_amdgcn_mfma_f32_16x16x32_f16(A[kk], bfr[2][kk], c2, 0, 0, 0); \
        c3 = __builtin_amdgcn_mfma_f32_16x16x32_f16(A[kk], bfr[3][kk], c3, 0, 0, 0); } }

#define EPI1(t, cc) { \
    esum[t] += (ex2(__builtin_fmaf(cc[0], L2E_T, -L2E_T)) \
              + ex2(__builtin_fmaf(cc[1], L2E_T, -L2E_T))) \
             + (ex2(__builtin_fmaf(cc[2], L2E_T, -L2E_T)) \
              + ex2(__builtin_fmaf(cc[3], L2E_T, -L2E_T))); }

#define EPI4(c0, c1, c2, c3) { EPI1(0, c0); EPI1(1, c1); EPI1(2, c2); EPI1(3, c3); }

    f16x8 af0[4], af1[4];
    LOADT(af0, 0);

    for (int s = 0; s < nsub; s += 2) {
        {   // subtile s (af0); prefetch s+1 between MFMA and epilogue
            f32x4 c0 = {0,0,0,0}, c1 = {0,0,0,0}, c2 = {0,0,0,0}, c3 = {0,0,0,0};
            MFMA16(af0, c0, c1, c2, c3);
            LOADT(af1, s + 1);               // nsub even: s+1 always valid
            EPI4(c0, c1, c2, c3);
        }
        {   // subtile s+1 (af1); prefetch s+2
            f32x4 c0 = {0,0,0,0}, c1 = {0,0,0,0}, c2 = {0,0,0,0}, c3 = {0,0,0,0};
            MFMA16(af1, c0, c1, c2, c3);
            if (s + 2 < nsub) LOADT(af0, s + 2);
            EPI4(c0, c1, c2, c3);
        }
    }
#undef LOADT
#undef MFMA16
#undef EPI1
#undef EPI4

    // fold lane groups (bits 4,5 = different j rows of the same i)
    #pragma unroll
    for (int t = 0; t < 4; ++t) {
        float e = esum[t];
        e += __shfl_xor(e, 16); e += __shfl_xor(e, 32);
        if (lane < 16)
            Epart[(size_t)blockIdx.y * M + ibase + t * 16 + lane] = e;
    }
}

// ---- per-row loss term: E from partials, P from G-dot; exact self-term ----
__global__ __launch_bounds__(256)
void final_fused(const _Float16* __restrict__ fh, const float* __restrict__ Epart,
                 const int* __restrict__ labm, const int* __restrict__ hist,
                 const float* __restrict__ G, float* __restrict__ out, int M)
{
    __shared__ float red[4];
    int i = (blockIdx.x * 256 + threadIdx.x) >> 6;   // wave per row
    int lane = threadIdx.x & 63;
    int lb = labm[i];
    f16x2 h = *reinterpret_cast<const f16x2*>(&fh[(size_t)i * DD + lane * 2]);
    float x0 = (float)h[0], x1 = (float)h[1];
    float2 g = *reinterpret_cast<const float2*>(&G[lb * DD + lane * 2]);
    float aii = x0 * x0 + x1 * x1;     // f16 self-dot in fp32 (matches MFMA a_ii)
    float gd  = x0 * g.x + x1 * g.y;   // f_i . G[lab_i] (includes self)
    #pragma unroll
    for (int m = 1; m < 64; m <<= 1) {
        aii += __shfl_xor(aii, m);
        gd  += __shfl_xor(gd, m);
    }
    float e = (lane < NSPLIT) ? Epart[(size_t)lane * M + i] : 0.f;
    #pragma unroll
    for (int m = 1; m < NSPLIT; m <<= 1) e += __shfl_xor(e, m);
    float term = 0.f;
    if (lane == 0) {
        float cnt = (float)(hist[lb] - 1);
        float E = e - ex2(__builtin_fmaf(aii, L2E_T, -L2E_T));  // drop self exp
        term = (SHIFT + logf(E)) - SHIFT * (gd - aii) / cnt;    // drop self dot
    }
    int wv = threadIdx.x >> 6;
    if (lane == 0) red[wv] = term;
    __syncthreads();
    if (threadIdx.x == 0)
        atomicAdd(out, (red[0] + red[1] + red[2] + red[3]) / (float)M);
}

extern "C" void kernel_launch(void* const* d_in, const int* in_sizes, int n_in,
                              void* d_out, int out_size, void* d_ws, size_t ws_size,
                              hipStream_t stream)
{
    const float* feats = (const float*)d_in[0];
    const int* labels = (const int*)d_in[1];
    const int Bn = in_sizes[1];
    const int M = in_sizes[0] / DD;    // 8192
    const int nrep = M / Bn;           // 2

    char* ws = (char*)d_ws;
    _Float16* fh = (_Float16*)ws;
    size_t off = (size_t)M * DD * sizeof(_Float16);
    int* labm = (int*)(ws + off); off += (size_t)M * sizeof(int);
    off = (off + 255) & ~(size_t)255;
    float* G = (float*)(ws + off); off += (size_t)NBINS * DD * sizeof(float);
    int* hist = (int*)(ws + off); off += (size_t)NBINS * sizeof(int);
    float* Epart = (float*)(ws + off); off += (size_t)NSPLIT * M * sizeof(float);

    // G and hist contiguous: one memset clears both
    hipMemsetAsync(G, 0, (size_t)NBINS * DD * sizeof(float) + NBINS * sizeof(int), stream);

    norm_kernel<<<M / 4, 256, 0, stream>>>(feats, labels, fh, labm, hist, G,
                                           (float*)d_out, M, nrep);

    const int jchunk = M / NSPLIT;     // 512 -> 32 subtiles per wave
    dim3 grid(M / 256, NSPLIT);        // 32 x 16 = 512 blocks (2/CU, 1 round)
    supcon_main<<<grid, 256, 0, stream>>>(fh, Epart, M, jchunk);

    final_fused<<<M / 4, 256, 0, stream>>>(fh, Epart, labm, hist, G, (float*)d_out, M);
}

// Round 11
// 85.796 us; speedup vs baseline: 1.2917x; 1.0003x over previous
//
#include <hip/hip_runtime.h>
#include <math.h>

#define DD 128
#define NSPLIT 16
#define NBINS 512
#define SHIFT 10.0f
#define L2E_T 14.4269504089f   // 10 * log2(e)

typedef _Float16 f16x8 __attribute__((ext_vector_type(8)));
typedef _Float16 f16x2 __attribute__((ext_vector_type(2)));
typedef float f32x4 __attribute__((ext_vector_type(4)));

// guard-free 2^x: args are in [-29, 0], no denorm/overflow concerns
__device__ __forceinline__ float ex2(float x) {
#if __has_builtin(__builtin_amdgcn_exp2f)
    return __builtin_amdgcn_exp2f(x);
#else
    return exp2f(x);
#endif
}

// ---- parallel zero of G+hist (hipMemsetAsync lowered to a ~41us serial
// fill kernel on this stack -- it was the single largest dispatch in R10) ----
__global__ __launch_bounds__(256)
void zero_kernel(float4* __restrict__ p, int n4)
{
    int i = blockIdx.x * 256 + threadIdx.x;
    if (i < n4) p[i] = make_float4(0.f, 0.f, 0.f, 0.f);
}

// ---- normalize rows -> f16, labels, histogram, label-sums G; zeroes d_out ----
__global__ __launch_bounds__(256)
void norm_kernel(const float* __restrict__ f, const int* __restrict__ labels,
                 _Float16* __restrict__ fh, int* __restrict__ labm,
                 int* __restrict__ hist, float* __restrict__ G,
                 float* __restrict__ out, int M, int nrep)
{
    if (blockIdx.x == 0 && threadIdx.x == 0) out[0] = 0.f;  // final runs 2 kernels later
    int gw = (blockIdx.x * 256 + threadIdx.x) >> 6;   // one wave per row
    int lane = threadIdx.x & 63;
    if (gw >= M) return;
    float2 v = *reinterpret_cast<const float2*>(&f[(size_t)gw * DD + lane * 2]);
    float ss = v.x * v.x + v.y * v.y;
    #pragma unroll
    for (int m = 1; m < 64; m <<= 1) ss += __shfl_xor(ss, m);
    float inv = 1.0f / fmaxf(sqrtf(ss), 1e-12f);
    float ox = v.x * inv, oy = v.y * inv;
    f16x2 h; h[0] = (_Float16)ox; h[1] = (_Float16)oy;
    *reinterpret_cast<f16x2*>(&fh[(size_t)gw * DD + lane * 2]) = h;
    int lb = labels[gw / nrep];
    atomicAdd(&G[lb * DD + lane * 2],     ox);
    atomicAdd(&G[lb * DD + lane * 2 + 1], oy);
    if (lane == 0) {
        labm[gw] = lb;
        if ((gw % nrep) == 0) atomicAdd(&hist[lb], nrep);  // one atomic per sample
    }
}

// ---- main: barrier-free f16 MFMA stream; epilogue = exp-sum ONLY ----
// R7's proven schedule (4 waves/block, 64 i-rows register-resident, 512
// blocks = 2/CU, (256,3), 2x ping-pong af0/af1 with prefetch between MFMA
// and epilogue). P-sum lives in the final kernel via G: epilogue is
// 3 ops/logit (fma, raw v_exp_f32, add). Self-pair subtracted in final.
__global__ __launch_bounds__(256, 3)
void supcon_main(const _Float16* __restrict__ fh, float* __restrict__ Epart,
                 int M, int jchunk)
{
    const int lane = threadIdx.x & 63;
    const int w = threadIdx.x >> 6;
    const int ibase = blockIdx.x * 256 + w * 64;
    const int rowsel = lane & 15;
    const int ksel = (lane >> 4) * 8;  // f16 k-offset within a 32-wide K step

    // register-resident Fi fragments: 4 subtiles x 4 K-steps = 64 regs
    f16x8 bfr[4][4];
    #pragma unroll
    for (int t = 0; t < 4; ++t)
        #pragma unroll
        for (int kk = 0; kk < 4; ++kk)
            bfr[t][kk] = *reinterpret_cast<const f16x8*>(
                &fh[(size_t)(ibase + t * 16 + rowsel) * DD + kk * 32 + ksel]);

    float esum[4] = {0.f, 0.f, 0.f, 0.f};

    const int j0 = blockIdx.y * jchunk;
    const _Float16* aptr = fh + (size_t)(j0 + rowsel) * DD + ksel;
    const int nsub = jchunk >> 4;      // 32 subtiles (even)

#define LOADT(A, s) { \
    _Pragma("unroll") for (int kk = 0; kk < 4; ++kk) \
        A[kk] = *reinterpret_cast<const f16x8*>(aptr + (size_t)(s) * 16 * DD + kk * 32); }

#define MFMA16(A, c0, c1, c2, c3) { \
    _Pragma("unroll") for (int kk = 0; kk < 4; ++kk) { \
        c0 = __builtin_amdgcn_mfma_f32_16x16x32_f16(A[kk], bfr[0][kk], c0, 0, 0, 0); \
        c1 = __builtin_amdgcn_mfma_f32_16x16x32_f16(A[kk], bfr[1][kk], c1, 0, 0, 0); \
        c2 = __builtin_amdgcn_mfma_f32_16x16x32_f16(A[kk], bfr[2][kk], c2, 0, 0, 0); \
        c3 = __builtin_amdgcn_mfma_f32_16x16x32_f16(A[kk], bfr[3][kk], c3, 0, 0, 0); } }

#define EPI1(t, cc) { \
    esum[t] += (ex2(__builtin_fmaf(cc[0], L2E_T, -L2E_T)) \
              + ex2(__builtin_fmaf(cc[1], L2E_T, -L2E_T))) \
             + (ex2(__builtin_fmaf(cc[2], L2E_T, -L2E_T)) \
              + ex2(__builtin_fmaf(cc[3], L2E_T, -L2E_T))); }

#define EPI4(c0, c1, c2, c3) { EPI1(0, c0); EPI1(1, c1); EPI1(2, c2); EPI1(3, c3); }

    f16x8 af0[4], af1[4];
    LOADT(af0, 0);

    for (int s = 0; s < nsub; s += 2) {
        {   // subtile s (af0); prefetch s+1 between MFMA and epilogue
            f32x4 c0 = {0,0,0,0}, c1 = {0,0,0,0}, c2 = {0,0,0,0}, c3 = {0,0,0,0};
            MFMA16(af0, c0, c1, c2, c3);
            LOADT(af1, s + 1);               // nsub even: s+1 always valid
            EPI4(c0, c1, c2, c3);
        }
        {   // subtile s+1 (af1); prefetch s+2
            f32x4 c0 = {0,0,0,0}, c1 = {0,0,0,0}, c2 = {0,0,0,0}, c3 = {0,0,0,0};
            MFMA16(af1, c0, c1, c2, c3);
            if (s + 2 < nsub) LOADT(af0, s + 2);
            EPI4(c0, c1, c2, c3);
        }
    }
#undef LOADT
#undef MFMA16
#undef EPI1
#undef EPI4

    // fold lane groups (bits 4,5 = different j rows of the same i)
    #pragma unroll
    for (int t = 0; t < 4; ++t) {
        float e = esum[t];
        e += __shfl_xor(e, 16); e += __shfl_xor(e, 32);
        if (lane < 16)
            Epart[(size_t)blockIdx.y * M + ibase + t * 16 + lane] = e;
    }
}

// ---- per-row loss term: E from partials, P from G-dot; exact self-term ----
__global__ __launch_bounds__(256)
void final_fused(const _Float16* __restrict__ fh, const float* __restrict__ Epart,
                 const int* __restrict__ labm, const int* __restrict__ hist,
                 const float* __restrict__ G, float* __restrict__ out, int M)
{
    __shared__ float red[4];
    int i = (blockIdx.x * 256 + threadIdx.x) >> 6;   // wave per row
    int lane = threadIdx.x & 63;
    int lb = labm[i];
    f16x2 h = *reinterpret_cast<const f16x2*>(&fh[(size_t)i * DD + lane * 2]);
    float x0 = (float)h[0], x1 = (float)h[1];
    float2 g = *reinterpret_cast<const float2*>(&G[lb * DD + lane * 2]);
    float aii = x0 * x0 + x1 * x1;     // f16 self-dot in fp32 (matches MFMA a_ii)
    float gd  = x0 * g.x + x1 * g.y;   // f_i . G[lab_i] (includes self)
    #pragma unroll
    for (int m = 1; m < 64; m <<= 1) {
        aii += __shfl_xor(aii, m);
        gd  += __shfl_xor(gd, m);
    }
    float e = (lane < NSPLIT) ? Epart[(size_t)lane * M + i] : 0.f;
    #pragma unroll
    for (int m = 1; m < NSPLIT; m <<= 1) e += __shfl_xor(e, m);
    float term = 0.f;
    if (lane == 0) {
        float cnt = (float)(hist[lb] - 1);
        float E = e - ex2(__builtin_fmaf(aii, L2E_T, -L2E_T));  // drop self exp
        term = (SHIFT + logf(E)) - SHIFT * (gd - aii) / cnt;    // drop self dot
    }
    int wv = threadIdx.x >> 6;
    if (lane == 0) red[wv] = term;
    __syncthreads();
    if (threadIdx.x == 0)
        atomicAdd(out, (red[0] + red[1] + red[2] + red[3]) / (float)M);
}

extern "C" void kernel_launch(void* const* d_in, const int* in_sizes, int n_in,
                              void* d_out, int out_size, void* d_ws, size_t ws_size,
                              hipStream_t stream)
{
    const float* feats = (const float*)d_in[0];
    const int* labels = (const int*)d_in[1];
    const int Bn = in_sizes[1];
    const int M = in_sizes[0] / DD;    // 8192
    const int nrep = M / Bn;           // 2

    char* ws = (char*)d_ws;
    _Float16* fh = (_Float16*)ws;
    size_t off = (size_t)M * DD * sizeof(_Float16);
    int* labm = (int*)(ws + off); off += (size_t)M * sizeof(int);
    off = (off + 255) & ~(size_t)255;
    float* G = (float*)(ws + off); off += (size_t)NBINS * DD * sizeof(float);
    int* hist = (int*)(ws + off); off += (size_t)NBINS * sizeof(int);
    float* Epart = (float*)(ws + off); off += (size_t)NSPLIT * M * sizeof(float);

    // G and hist contiguous: one parallel zero kernel clears both (~2us;
    // hipMemsetAsync's fill kernel measured 41us in R10 -- critical path!)
    const int zero_n4 = (NBINS * DD * 4 + NBINS * 4) / 16;   // 16512 float4s
    zero_kernel<<<(zero_n4 + 255) / 256, 256, 0, stream>>>((float4*)G, zero_n4);

    norm_kernel<<<M / 4, 256, 0, stream>>>(feats, labels, fh, labm, hist, G,
                                           (float*)d_out, M, nrep);

    const int jchunk = M / NSPLIT;     // 512 -> 32 subtiles per wave
    dim3 grid(M / 256, NSPLIT);        // 32 x 16 = 512 blocks (2/CU, 1 round)
    supcon_main<<<grid, 256, 0, stream>>>(fh, Epart, M, jchunk);

    final_fused<<<M / 4, 256, 0, stream>>>(fh, Epart, labm, hist, G, (float*)d_out, M);
}

// Round 12
// 85.524 us; speedup vs baseline: 1.2958x; 1.0032x over previous
//
#include <hip/hip_runtime.h>
#include <math.h>

#define DD 128
#define NSPLIT 24
#define NBINS 512
#define SHIFT 10.0f
#define L2E_T 14.4269504089f   // 10 * log2(e)

typedef _Float16 f16x8 __attribute__((ext_vector_type(8)));
typedef _Float16 f16x2 __attribute__((ext_vector_type(2)));
typedef float f32x4 __attribute__((ext_vector_type(4)));

// guard-free 2^x: args are in [-29, 0], no denorm/overflow concerns
__device__ __forceinline__ float ex2(float x) {
#if __has_builtin(__builtin_amdgcn_exp2f)
    return __builtin_amdgcn_exp2f(x);
#else
    return exp2f(x);
#endif
}

// ---- tiny zero: hist (512 ints) + d_out; 1 block, ~1us ----
__global__ __launch_bounds__(256)
void zero_kernel(int* __restrict__ hist, float* __restrict__ out)
{
    hist[threadIdx.x] = 0;
    hist[256 + threadIdx.x] = 0;
    if (threadIdx.x == 0) out[0] = 0.f;
}

// ---- normalize rows -> f16, labels, histogram ----
__global__ __launch_bounds__(256)
void norm_kernel(const float* __restrict__ f, const int* __restrict__ labels,
                 _Float16* __restrict__ fh, int* __restrict__ labm,
                 int* __restrict__ hist, int M, int nrep)
{
    int gw = (blockIdx.x * 256 + threadIdx.x) >> 6;   // one wave per row
    int lane = threadIdx.x & 63;
    if (gw >= M) return;
    float2 v = *reinterpret_cast<const float2*>(&f[(size_t)gw * DD + lane * 2]);
    float ss = v.x * v.x + v.y * v.y;
    #pragma unroll
    for (int m = 1; m < 64; m <<= 1) ss += __shfl_xor(ss, m);
    float inv = 1.0f / fmaxf(sqrtf(ss), 1e-12f);
    f16x2 h; h[0] = (_Float16)(v.x * inv); h[1] = (_Float16)(v.y * inv);
    *reinterpret_cast<f16x2*>(&fh[(size_t)gw * DD + lane * 2]) = h;
    if (lane == 0) {
        int lb = labels[gw / nrep];
        labm[gw] = lb;
        if ((gw % nrep) == 0) atomicAdd(&hist[lb], nrep);  // one atomic per sample
    }
}

// ---- main: barrier-free f16 MFMA stream, fused exp-sum + masked P-sum ----
// R7's proven schedule: 4 waves/block, 64 i-rows/wave register-resident
// (bfr[4][4]), 2x ping-pong af0/af1 with prefetch issued between MFMA and
// epilogue, (256,3), no LDS/barriers. New vs R7: raw v_exp_f32 (no OCML
// guard; R10 validated) and grid 32x24 = 768 blocks = exactly 3 blocks/CU
// = 3 waves/SIMD (R7 ran 2/SIMD, grid-limited). NSPLIT=24 doesn't divide
// 512 subtiles evenly -> uneven ranges (8x22 + 16x21), ~5% imbalance.
// S^T via mfma(A=Fj, B=Fi): i = lane&15 (lane-local), j = (lane>>4)*4 + r.
// Self-pair included; final kernel subtracts it exactly.
__global__ __launch_bounds__(256, 3)
void supcon_main(const _Float16* __restrict__ fh, const int* __restrict__ labm,
                 float* __restrict__ Epart, float* __restrict__ Ppart,
                 int M, int nsub_total)
{
    const int lane = threadIdx.x & 63;
    const int w = threadIdx.x >> 6;
    const int ibase = blockIdx.x * 256 + w * 64;
    const int rowsel = lane & 15;
    const int grp = lane >> 4;
    const int ksel = grp * 8;      // f16 k-offset within a 32-wide K step

    // register-resident Fi fragments: 4 subtiles x 4 K-steps = 64 regs
    f16x8 bfr[4][4];
    #pragma unroll
    for (int t = 0; t < 4; ++t)
        #pragma unroll
        for (int kk = 0; kk < 4; ++kk)
            bfr[t][kk] = *reinterpret_cast<const f16x8*>(
                &fh[(size_t)(ibase + t * 16 + rowsel) * DD + kk * 32 + ksel]);

    int li[4];
    #pragma unroll
    for (int t = 0; t < 4; ++t) li[t] = labm[ibase + t * 16 + rowsel];

    float esum[4] = {0.f, 0.f, 0.f, 0.f};
    float psum[4] = {0.f, 0.f, 0.f, 0.f};

    // uneven subtile range for this j-split
    const int base = nsub_total / NSPLIT, rem = nsub_total % NSPLIT;
    const int by = blockIdx.y;
    const int s0 = by * base + (by < rem ? by : rem);
    const int send = s0 + base + (by < rem ? 1 : 0);

    const _Float16* aptr = fh + (size_t)rowsel * DD + ksel;  // + s*16*DD per subtile
    const int* lptr = labm + grp * 4;

#define LOADT(A, L, s) { \
    _Pragma("unroll") for (int kk = 0; kk < 4; ++kk) \
        A[kk] = *reinterpret_cast<const f16x8*>(aptr + (size_t)(s) * 16 * DD + kk * 32); \
    L = *reinterpret_cast<const int4*>(lptr + (s) * 16); }

#define MFMA16(A, c0, c1, c2, c3) { \
    _Pragma("unroll") for (int kk = 0; kk < 4; ++kk) { \
        c0 = __builtin_amdgcn_mfma_f32_16x16x32_f16(A[kk], bfr[0][kk], c0, 0, 0, 0); \
        c1 = __builtin_amdgcn_mfma_f32_16x16x32_f16(A[kk], bfr[1][kk], c1, 0, 0, 0); \
        c2 = __builtin_amdgcn_mfma_f32_16x16x32_f16(A[kk], bfr[2][kk], c2, 0, 0, 0); \
        c3 = __builtin_amdgcn_mfma_f32_16x16x32_f16(A[kk], bfr[3][kk], c3, 0, 0, 0); } }

#define EPI1(t, cc, L) { \
    esum[t] += (ex2(__builtin_fmaf(cc[0], L2E_T, -L2E_T)) \
              + ex2(__builtin_fmaf(cc[1], L2E_T, -L2E_T))) \
             + (ex2(__builtin_fmaf(cc[2], L2E_T, -L2E_T)) \
              + ex2(__builtin_fmaf(cc[3], L2E_T, -L2E_T))); \
    float p0 = (L.x == li[t]) ? cc[0] : 0.f; \
    float p1 = (L.y == li[t]) ? cc[1] : 0.f; \
    float p2 = (L.z == li[t]) ? cc[2] : 0.f; \
    float p3 = (L.w == li[t]) ? cc[3] : 0.f; \
    psum[t] += (p0 + p1) + (p2 + p3); }

#define EPI4(c0, c1, c2, c3, L) { \
    EPI1(0, c0, L); EPI1(1, c1, L); EPI1(2, c2, L); EPI1(3, c3, L); }

    f16x8 af0[4], af1[4];
    int4 lj0, lj1;
    LOADT(af0, lj0, s0);

    int s = s0;
    for (; s + 1 < send; s += 2) {
        {   // subtile s (af0); prefetch s+1 between MFMA and epilogue
            f32x4 c0 = {0,0,0,0}, c1 = {0,0,0,0}, c2 = {0,0,0,0}, c3 = {0,0,0,0};
            MFMA16(af0, c0, c1, c2, c3);
            LOADT(af1, lj1, s + 1);
            EPI4(c0, c1, c2, c3, lj0);
        }
        {   // subtile s+1 (af1); prefetch s+2
            f32x4 c0 = {0,0,0,0}, c1 = {0,0,0,0}, c2 = {0,0,0,0}, c3 = {0,0,0,0};
            MFMA16(af1, c0, c1, c2, c3);
            if (s + 2 < send) LOADT(af0, lj0, s + 2);
            EPI4(c0, c1, c2, c3, lj1);
        }
    }
    if (s < send) {   // odd-count tail: af0/lj0 hold subtile s
        f32x4 c0 = {0,0,0,0}, c1 = {0,0,0,0}, c2 = {0,0,0,0}, c3 = {0,0,0,0};
        MFMA16(af0, c0, c1, c2, c3);
        EPI4(c0, c1, c2, c3, lj0);
    }
#undef LOADT
#undef MFMA16
#undef EPI1
#undef EPI4

    // fold lane groups (bits 4,5 = different j rows of the same i)
    #pragma unroll
    for (int t = 0; t < 4; ++t) {
        float e = esum[t], p = psum[t];
        e += __shfl_xor(e, 16); e += __shfl_xor(e, 32);
        p += __shfl_xor(p, 16); p += __shfl_xor(p, 32);
        if (lane < 16) {
            size_t o = (size_t)by * M + ibase + t * 16 + lane;
            Epart[o] = e;
            Ppart[o] = p;
        }
    }
}

// ---- per-row loss term (exact self-term subtraction) + global reduce ----
__global__ __launch_bounds__(256)
void final_fused(const _Float16* __restrict__ fh, const float* __restrict__ Epart,
                 const float* __restrict__ Ppart, const int* __restrict__ labm,
                 const int* __restrict__ hist, float* __restrict__ out, int M)
{
    __shared__ float red[4];
    int i = (blockIdx.x * 256 + threadIdx.x) >> 6;   // wave per row
    int lane = threadIdx.x & 63;
    f16x2 h = *reinterpret_cast<const f16x2*>(&fh[(size_t)i * DD + lane * 2]);
    float x0 = (float)h[0], x1 = (float)h[1];
    float aii = x0 * x0 + x1 * x1;                   // f16 self-dot in fp32
    #pragma unroll
    for (int m = 1; m < 64; m <<= 1) aii += __shfl_xor(aii, m);
    float ep = 0.f;
    if (lane < NSPLIT) ep = Epart[(size_t)lane * M + i];
    else if (lane >= 32 && lane < 32 + NSPLIT) ep = Ppart[(size_t)(lane - 32) * M + i];
    #pragma unroll
    for (int m = 1; m < 32; m <<= 1) ep += __shfl_xor(ep, m);  // within 32-halves
    float P = __shfl(ep, 32);
    float term = 0.f;
    if (lane == 0) {
        int lb = labm[i];
        float cnt = (float)(hist[lb] - 1);
        float E = ep - ex2(__builtin_fmaf(aii, L2E_T, -L2E_T)); // drop self exp
        float Pc = SHIFT * (P - aii);                           // drop self dot
        term = (SHIFT + logf(E)) - Pc / cnt;
    }
    int wv = threadIdx.x >> 6;
    if (lane == 0) red[wv] = term;
    __syncthreads();
    if (threadIdx.x == 0)
        atomicAdd(out, (red[0] + red[1] + red[2] + red[3]) / (float)M);
}

extern "C" void kernel_launch(void* const* d_in, const int* in_sizes, int n_in,
                              void* d_out, int out_size, void* d_ws, size_t ws_size,
                              hipStream_t stream)
{
    const float* feats = (const float*)d_in[0];
    const int* labels = (const int*)d_in[1];
    const int Bn = in_sizes[1];
    const int M = in_sizes[0] / DD;    // 8192
    const int nrep = M / Bn;           // 2

    char* ws = (char*)d_ws;
    _Float16* fh = (_Float16*)ws;
    size_t off = (size_t)M * DD * sizeof(_Float16);
    int* labm = (int*)(ws + off); off += (size_t)M * sizeof(int);
    int* hist = (int*)(ws + off); off += (size_t)NBINS * sizeof(int);
    off = (off + 255) & ~(size_t)255;
    float* Epart = (float*)(ws + off); off += (size_t)NSPLIT * M * sizeof(float);
    float* Ppart = (float*)(ws + off); off += (size_t)NSPLIT * M * sizeof(float);

    zero_kernel<<<1, 256, 0, stream>>>(hist, (float*)d_out);

    norm_kernel<<<M / 4, 256, 0, stream>>>(feats, labels, fh, labm, hist, M, nrep);

    const int nsub_total = M / 16;     // 512 j-subtiles split unevenly over 24
    dim3 grid(M / 256, NSPLIT);        // 32 x 24 = 768 blocks (3/CU, 1 round)
    supcon_main<<<grid, 256, 0, stream>>>(fh, labm, Epart, Ppart, M, nsub_total);

    final_fused<<<M / 4, 256, 0, stream>>>(fh, Epart, Ppart, labm, hist, (float*)d_out, M);
}

// Round 13
// 58.555 us; speedup vs baseline: 1.8926x; 1.4606x over previous
//
#include <hip/hip_runtime.h>
#include <math.h>

#define DD 128
#define NSPLIT 24
#define NBINS 512
#define SHIFT 10.0f
#define L2E_T 14.4269504089f   // 10 * log2(e)

typedef _Float16 f16x8 __attribute__((ext_vector_type(8)));
typedef _Float16 f16x2 __attribute__((ext_vector_type(2)));
typedef float f32x4 __attribute__((ext_vector_type(4)));

// guard-free 2^x: args are in [-29, 0], no denorm/overflow concerns
__device__ __forceinline__ float ex2(float x) {
#if __has_builtin(__builtin_amdgcn_exp2f)
    return __builtin_amdgcn_exp2f(x);
#else
    return exp2f(x);
#endif
}

// ---- tiny zero: hist (512 ints) + d_out; 1 block, ~1us ----
__global__ __launch_bounds__(256)
void zero_kernel(int* __restrict__ hist, float* __restrict__ out)
{
    hist[threadIdx.x] = 0;
    hist[256 + threadIdx.x] = 0;
    if (threadIdx.x == 0) out[0] = 0.f;
}

// ---- normalize rows -> f16, labels, histogram ----
__global__ __launch_bounds__(256)
void norm_kernel(const float* __restrict__ f, const int* __restrict__ labels,
                 _Float16* __restrict__ fh, int* __restrict__ labm,
                 int* __restrict__ hist, int M, int nrep)
{
    int gw = (blockIdx.x * 256 + threadIdx.x) >> 6;   // one wave per row
    int lane = threadIdx.x & 63;
    if (gw >= M) return;
    float2 v = *reinterpret_cast<const float2*>(&f[(size_t)gw * DD + lane * 2]);
    float ss = v.x * v.x + v.y * v.y;
    #pragma unroll
    for (int m = 1; m < 64; m <<= 1) ss += __shfl_xor(ss, m);
    float inv = 1.0f / fmaxf(sqrtf(ss), 1e-12f);
    f16x2 h; h[0] = (_Float16)(v.x * inv); h[1] = (_Float16)(v.y * inv);
    *reinterpret_cast<f16x2*>(&fh[(size_t)gw * DD + lane * 2]) = h;
    if (lane == 0) {
        int lb = labels[gw / nrep];
        labm[gw] = lb;
        if ((gw % nrep) == 0) atomicAdd(&hist[lb], nrep);  // one atomic per sample
    }
}

// ---- main: barrier-free f16 MFMA stream, fused exp-sum + masked P-sum ----
// FROZEN from R12 (best clean: 42.9us, VGPR 80, zero spill). 4 waves/block,
// 64 i-rows/wave register-resident, 2x ping-pong af0/af1, (256,3), raw
// v_exp_f32, grid 32x24 = 768 = 3 blocks/CU. Self-pair subtracted in final.
__global__ __launch_bounds__(256, 3)
void supcon_main(const _Float16* __restrict__ fh, const int* __restrict__ labm,
                 float* __restrict__ Epart, float* __restrict__ Ppart,
                 int M, int nsub_total)
{
    const int lane = threadIdx.x & 63;
    const int w = threadIdx.x >> 6;
    const int ibase = blockIdx.x * 256 + w * 64;
    const int rowsel = lane & 15;
    const int grp = lane >> 4;
    const int ksel = grp * 8;      // f16 k-offset within a 32-wide K step

    // register-resident Fi fragments: 4 subtiles x 4 K-steps = 64 regs
    f16x8 bfr[4][4];
    #pragma unroll
    for (int t = 0; t < 4; ++t)
        #pragma unroll
        for (int kk = 0; kk < 4; ++kk)
            bfr[t][kk] = *reinterpret_cast<const f16x8*>(
                &fh[(size_t)(ibase + t * 16 + rowsel) * DD + kk * 32 + ksel]);

    int li[4];
    #pragma unroll
    for (int t = 0; t < 4; ++t) li[t] = labm[ibase + t * 16 + rowsel];

    float esum[4] = {0.f, 0.f, 0.f, 0.f};
    float psum[4] = {0.f, 0.f, 0.f, 0.f};

    // uneven subtile range for this j-split
    const int base = nsub_total / NSPLIT, rem = nsub_total % NSPLIT;
    const int by = blockIdx.y;
    const int s0 = by * base + (by < rem ? by : rem);
    const int send = s0 + base + (by < rem ? 1 : 0);

    const _Float16* aptr = fh + (size_t)rowsel * DD + ksel;  // + s*16*DD per subtile
    const int* lptr = labm + grp * 4;

#define LOADT(A, L, s) { \
    _Pragma("unroll") for (int kk = 0; kk < 4; ++kk) \
        A[kk] = *reinterpret_cast<const f16x8*>(aptr + (size_t)(s) * 16 * DD + kk * 32); \
    L = *reinterpret_cast<const int4*>(lptr + (s) * 16); }

#define MFMA16(A, c0, c1, c2, c3) { \
    _Pragma("unroll") for (int kk = 0; kk < 4; ++kk) { \
        c0 = __builtin_amdgcn_mfma_f32_16x16x32_f16(A[kk], bfr[0][kk], c0, 0, 0, 0); \
        c1 = __builtin_amdgcn_mfma_f32_16x16x32_f16(A[kk], bfr[1][kk], c1, 0, 0, 0); \
        c2 = __builtin_amdgcn_mfma_f32_16x16x32_f16(A[kk], bfr[2][kk], c2, 0, 0, 0); \
        c3 = __builtin_amdgcn_mfma_f32_16x16x32_f16(A[kk], bfr[3][kk], c3, 0, 0, 0); } }

#define EPI1(t, cc, L) { \
    esum[t] += (ex2(__builtin_fmaf(cc[0], L2E_T, -L2E_T)) \
              + ex2(__builtin_fmaf(cc[1], L2E_T, -L2E_T))) \
             + (ex2(__builtin_fmaf(cc[2], L2E_T, -L2E_T)) \
              + ex2(__builtin_fmaf(cc[3], L2E_T, -L2E_T))); \
    float p0 = (L.x == li[t]) ? cc[0] : 0.f; \
    float p1 = (L.y == li[t]) ? cc[1] : 0.f; \
    float p2 = (L.z == li[t]) ? cc[2] : 0.f; \
    float p3 = (L.w == li[t]) ? cc[3] : 0.f; \
    psum[t] += (p0 + p1) + (p2 + p3); }

#define EPI4(c0, c1, c2, c3, L) { \
    EPI1(0, c0, L); EPI1(1, c1, L); EPI1(2, c2, L); EPI1(3, c3, L); }

    f16x8 af0[4], af1[4];
    int4 lj0, lj1;
    LOADT(af0, lj0, s0);

    int s = s0;
    for (; s + 1 < send; s += 2) {
        {   // subtile s (af0); prefetch s+1 between MFMA and epilogue
            f32x4 c0 = {0,0,0,0}, c1 = {0,0,0,0}, c2 = {0,0,0,0}, c3 = {0,0,0,0};
            MFMA16(af0, c0, c1, c2, c3);
            LOADT(af1, lj1, s + 1);
            EPI4(c0, c1, c2, c3, lj0);
        }
        {   // subtile s+1 (af1); prefetch s+2
            f32x4 c0 = {0,0,0,0}, c1 = {0,0,0,0}, c2 = {0,0,0,0}, c3 = {0,0,0,0};
            MFMA16(af1, c0, c1, c2, c3);
            if (s + 2 < send) LOADT(af0, lj0, s + 2);
            EPI4(c0, c1, c2, c3, lj1);
        }
    }
    if (s < send) {   // odd-count tail: af0/lj0 hold subtile s
        f32x4 c0 = {0,0,0,0}, c1 = {0,0,0,0}, c2 = {0,0,0,0}, c3 = {0,0,0,0};
        MFMA16(af0, c0, c1, c2, c3);
        EPI4(c0, c1, c2, c3, lj0);
    }
#undef LOADT
#undef MFMA16
#undef EPI1
#undef EPI4

    // fold lane groups (bits 4,5 = different j rows of the same i)
    #pragma unroll
    for (int t = 0; t < 4; ++t) {
        float e = esum[t], p = psum[t];
        e += __shfl_xor(e, 16); e += __shfl_xor(e, 32);
        p += __shfl_xor(p, 16); p += __shfl_xor(p, 32);
        if (lane < 16) {
            size_t o = (size_t)by * M + ibase + t * 16 + lane;
            Epart[o] = e;
            Ppart[o] = p;
        }
    }
}

// ---- per-row loss term: ONE THREAD per row (32 blocks), coalesced partial
// reads, block-reduce, ONE atomic per block (R12 did 2048 contended atomics
// to d_out[0] -- suspected ~15-25us of the fixed residual) ----
__global__ __launch_bounds__(256)
void final_fused(const _Float16* __restrict__ fh, const float* __restrict__ Epart,
                 const float* __restrict__ Ppart, const int* __restrict__ labm,
                 const int* __restrict__ hist, float* __restrict__ out, int M)
{
    __shared__ float red[4];
    const int i = blockIdx.x * 256 + threadIdx.x;   // one row per thread
    // self-dot a_ii from f16 row (matches the MFMA diagonal term)
    float aii = 0.f;
    const f16x8* fr = reinterpret_cast<const f16x8*>(&fh[(size_t)i * DD]);
    #pragma unroll
    for (int k = 0; k < 16; ++k) {
        f16x8 hv = fr[k];
        #pragma unroll
        for (int e = 0; e < 8; ++e) {
            float x = (float)hv[e];
            aii = __builtin_fmaf(x, x, aii);
        }
    }
    // partial sums: coalesced (consecutive i across lanes, same k)
    float E = 0.f, P = 0.f;
    #pragma unroll
    for (int k = 0; k < NSPLIT; ++k) {
        E += Epart[(size_t)k * M + i];
        P += Ppart[(size_t)k * M + i];
    }
    int lb = labm[i];
    float cnt = (float)(hist[lb] - 1);
    E -= ex2(__builtin_fmaf(aii, L2E_T, -L2E_T));   // drop self exp
    float term = (SHIFT + logf(E)) - SHIFT * (P - aii) / cnt;

    #pragma unroll
    for (int m = 1; m < 64; m <<= 1) term += __shfl_xor(term, m);
    int lane = threadIdx.x & 63, wv = threadIdx.x >> 6;
    if (lane == 0) red[wv] = term;
    __syncthreads();
    if (threadIdx.x == 0)
        atomicAdd(out, (red[0] + red[1] + red[2] + red[3]) / (float)M);
}

extern "C" void kernel_launch(void* const* d_in, const int* in_sizes, int n_in,
                              void* d_out, int out_size, void* d_ws, size_t ws_size,
                              hipStream_t stream)
{
    const float* feats = (const float*)d_in[0];
    const int* labels = (const int*)d_in[1];
    const int Bn = in_sizes[1];
    const int M = in_sizes[0] / DD;    // 8192
    const int nrep = M / Bn;           // 2

    char* ws = (char*)d_ws;
    _Float16* fh = (_Float16*)ws;
    size_t off = (size_t)M * DD * sizeof(_Float16);
    int* labm = (int*)(ws + off); off += (size_t)M * sizeof(int);
    int* hist = (int*)(ws + off); off += (size_t)NBINS * sizeof(int);
    off = (off + 255) & ~(size_t)255;
    float* Epart = (float*)(ws + off); off += (size_t)NSPLIT * M * sizeof(float);
    float* Ppart = (float*)(ws + off); off += (size_t)NSPLIT * M * sizeof(float);

    zero_kernel<<<1, 256, 0, stream>>>(hist, (float*)d_out);

    norm_kernel<<<M / 4, 256, 0, stream>>>(feats, labels, fh, labm, hist, M, nrep);

    const int nsub_total = M / 16;     // 512 j-subtiles split unevenly over 24
    dim3 grid(M / 256, NSPLIT);        // 32 x 24 = 768 blocks (3/CU, 1 round)
    supcon_main<<<grid, 256, 0, stream>>>(fh, labm, Epart, Ppart, M, nsub_total);

    final_fused<<<M / 256, 256, 0, stream>>>(fh, Epart, Ppart, labm, hist,
                                             (float*)d_out, M);
}